// Round 8
// baseline (296.507 us; speedup 1.0000x reference)
//
#include <hip/hip_runtime.h>

// Deformable attention, single head, Lv=2, P=4 — three-kernel structure.
//   query [1,40000,256], value [2,32768,256], ref_pts [1,40000,2,2],
//   W_off [256,16], b_off[16], W_attn [256,8], b_attn[8], out [1,40000,256] f32.
// K0 (setup):  transpose W into ws (24x256 row-major) + concat biases. ~2 us.
// K1 (proj):   register-blocked GEMM (64q x 24 out per block) + fused
//              softmax/record epilogue. W via uniform scalar loads (no LDS),
//              Q-tile transposed in LDS (conflict-free b32 reads). ~15-25 us.
// K2 (sample): round-1 proven gather kernel (97 us, VGPR=32), byte-identical.

#define C_DIM 256
#define Q_DIM 40000
#define H_IMG 128
#define W_IMG 256
#define NV    (H_IMG * W_IMG)

// d_ws layout (bytes):
//   [0, 5120000)           samples: 40000 x 8 x float4  (proven region)
//   [5120000, 5144576)     Wt: 24 x 256 f32 (row j = output col j, contiguous K)
//   [5144576, 5144672)     bias_cat[24]
#define WS_SAMPLES_OFF 0
#define WS_WT_OFF      5120000
#define WS_BIAS_OFF    5144576

// ---------------------------------------------------------------------------
// Kernel 0: W transpose + bias concat (1 block, trivial).
// ---------------------------------------------------------------------------
__global__ __launch_bounds__(256) void setup_w_kernel(
    const float* __restrict__ Woff,  const float* __restrict__ boff,
    const float* __restrict__ Wattn, const float* __restrict__ battn,
    float* __restrict__ Wt, float* __restrict__ bias)
{
    const int tid = threadIdx.x;
    for (int i = tid; i < 4096; i += 256) {          // W_off [256,16] -> rows 0..15
        int c = i >> 4, j = i & 15;
        Wt[j * 256 + c] = Woff[i];
    }
    for (int i = tid; i < 2048; i += 256) {          // W_attn [256,8] -> rows 16..23
        int c = i >> 3, j = i & 7;
        Wt[(16 + j) * 256 + c] = Wattn[i];
    }
    if (tid < 16)      bias[tid] = boff[tid];
    else if (tid < 24) bias[tid] = battn[tid - 16];
}

// ---------------------------------------------------------------------------
// Kernel 1: projection GEMM + softmax + sample records.
// Block: 256 thr = 4 waves; tile = 64 queries x 24 outputs.
// Wave c4 owns output cols [c4*6, c4*6+6): W values wave-uniform -> SGPRs.
// ---------------------------------------------------------------------------
__global__ __launch_bounds__(256) void proj_gemm_kernel(
    const float* __restrict__ query,
    const float* __restrict__ rp,
    const float* __restrict__ Wt,      // [24][256] in ws
    const float* __restrict__ bias,    // [24] in ws
    float4* __restrict__ samples)      // [Q][8] in ws
{
    __shared__ float Qt[32 * 65];      // transposed k-chunk: Qt[k][r], pad 65
    __shared__ float Lt[64 * 25];      // logit exchange: Lt[r][j], pad 25

    const int tid = threadIdx.x;
    const int r   = tid & 63;          // query row within tile (= lane)
    const int c4  = tid >> 6;          // wave id -> column group
    const int q0  = blockIdx.x * 64;   // 625 blocks * 64 = 40000 exact

    // acc init = bias (bias folded into accumulation start)
    const float* brow = bias + c4 * 6;
    float acc0 = brow[0], acc1 = brow[1], acc2 = brow[2];
    float acc3 = brow[3], acc4 = brow[4], acc5 = brow[5];

    const float* wrow = Wt + (c4 * 6) * 256;   // 6 contiguous-K rows

    for (int kc = 0; kc < 8; ++kc) {           // K = 256 in chunks of 32
        // ---- stage Q-tile chunk, transposed: Qt[k][row] ----
        {
            const int rw = tid >> 3;           // 0..31
            const int f  = tid & 7;            // 0..7 (16B each -> 32 floats)
#pragma unroll
            for (int p = 0; p < 2; ++p) {
                const int row = rw + 32 * p;
                float4 v = *reinterpret_cast<const float4*>(
                    query + (size_t)(q0 + row) * C_DIM + kc * 32 + f * 4);
                Qt[(f * 4 + 0) * 65 + row] = v.x;
                Qt[(f * 4 + 1) * 65 + row] = v.y;
                Qt[(f * 4 + 2) * 65 + row] = v.z;
                Qt[(f * 4 + 3) * 65 + row] = v.w;
            }
        }
        __syncthreads();
        // ---- 32-step inner: 1 conflict-free LDS read + 6 scalar-W fma ----
        const float* wk = wrow + kc * 32;
#pragma unroll
        for (int k = 0; k < 32; ++k) {
            const float qv = Qt[k * 65 + r];
            acc0 = fmaf(wk[0 * 256 + k], qv, acc0);
            acc1 = fmaf(wk[1 * 256 + k], qv, acc1);
            acc2 = fmaf(wk[2 * 256 + k], qv, acc2);
            acc3 = fmaf(wk[3 * 256 + k], qv, acc3);
            acc4 = fmaf(wk[4 * 256 + k], qv, acc4);
            acc5 = fmaf(wk[5 * 256 + k], qv, acc5);
        }
        __syncthreads();
    }

    // ---- exchange logits through LDS: Lt[r][col] ----
    {
        float* Lr = Lt + r * 25 + c4 * 6;
        Lr[0] = acc0; Lr[1] = acc1; Lr[2] = acc2;
        Lr[3] = acc3; Lr[4] = acc4; Lr[5] = acc5;
    }
    __syncthreads();

    // ---- epilogue: one thread per query (wave 0) ----
    if (tid < 64) {
        const int q = q0 + tid;
        float s[24];
#pragma unroll
        for (int j = 0; j < 24; ++j) s[j] = Lt[tid * 25 + j];

        float4 rp4 = *reinterpret_cast<const float4*>(rp + (size_t)q * 4); // l0x,l0y,l1x,l1y

        float mx = s[16];
#pragma unroll
        for (int k = 1; k < 8; ++k) mx = fmaxf(mx, s[16 + k]);
        float e[8], den = 0.f;
#pragma unroll
        for (int k = 0; k < 8; ++k) { e[k] = __expf(s[16 + k] - mx); den += e[k]; }
        const float rd = 1.0f / den;

#pragma unroll
        for (int smp = 0; smp < 8; ++smp) {
            const float refx = (smp >= 4) ? rp4.z : rp4.x;
            const float refy = (smp >= 4) ? rp4.w : rp4.y;
            const float ix = refx * (float)W_IMG + s[2 * smp]     - 0.5f;
            const float iy = refy * (float)H_IMG + s[2 * smp + 1] - 0.5f;
            samples[(size_t)q * 8 + smp] = make_float4(ix, iy, e[smp] * rd, 0.f);
        }
    }
}

// ---------------------------------------------------------------------------
// Kernel 2: bilinear gather + weighted accumulate (round-1 proven version).
// One wave per query; lane owns 4 consecutive channels -> coalesced 1KB loads.
// ---------------------------------------------------------------------------
__global__ __launch_bounds__(256) void deform_sample_kernel(
    const float* __restrict__ value,    // [2, NV, 256]
    const float4* __restrict__ samples, // [Q, 8]
    float* __restrict__ out)            // [Q, 256]
{
    const int lane = threadIdx.x & 63;
    const int q = (blockIdx.x * blockDim.x + threadIdx.x) >> 6;
    if (q >= Q_DIM) return;

    float4 acc = make_float4(0.f, 0.f, 0.f, 0.f);

#pragma unroll
    for (int smp = 0; smp < 8; ++smp) {
        float4 rec = samples[(size_t)q * 8 + smp];  // broadcast load
        const float* base = value + (size_t)(smp >> 2) * ((size_t)NV * C_DIM);

        float ix = rec.x, iy = rec.y, aw = rec.z;
        float x0f = floorf(ix), y0f = floorf(iy);
        float fx = ix - x0f, fy = iy - y0f;
        int x0 = (int)x0f, y0 = (int)y0f;
        int x1 = x0 + 1,   y1 = y0 + 1;

        bool vx0 = (unsigned)x0 < W_IMG;
        bool vx1 = (unsigned)x1 < W_IMG;
        bool vy0 = (unsigned)y0 < H_IMG;
        bool vy1 = (unsigned)y1 < H_IMG;

        int xc0 = min(max(x0, 0), W_IMG - 1);
        int xc1 = min(max(x1, 0), W_IMG - 1);
        int yc0 = min(max(y0, 0), H_IMG - 1);
        int yc1 = min(max(y1, 0), H_IMG - 1);

        float wx0 = 1.f - fx, wx1 = fx;
        float wy0 = 1.f - fy, wy1 = fy;
        float w00 = (vx0 && vy0) ? wx0 * wy0 * aw : 0.f;
        float w01 = (vx1 && vy0) ? wx1 * wy0 * aw : 0.f;
        float w10 = (vx0 && vy1) ? wx0 * wy1 * aw : 0.f;
        float w11 = (vx1 && vy1) ? wx1 * wy1 * aw : 0.f;

        const int ch = lane * 4;
        float4 v00 = *reinterpret_cast<const float4*>(base + (size_t)(yc0 * W_IMG + xc0) * C_DIM + ch);
        float4 v01 = *reinterpret_cast<const float4*>(base + (size_t)(yc0 * W_IMG + xc1) * C_DIM + ch);
        float4 v10 = *reinterpret_cast<const float4*>(base + (size_t)(yc1 * W_IMG + xc0) * C_DIM + ch);
        float4 v11 = *reinterpret_cast<const float4*>(base + (size_t)(yc1 * W_IMG + xc1) * C_DIM + ch);

        acc.x += w00 * v00.x + w01 * v01.x + w10 * v10.x + w11 * v11.x;
        acc.y += w00 * v00.y + w01 * v01.y + w10 * v10.y + w11 * v11.y;
        acc.z += w00 * v00.z + w01 * v01.z + w10 * v10.z + w11 * v11.z;
        acc.w += w00 * v00.w + w01 * v01.w + w10 * v10.w + w11 * v11.w;
    }

    *reinterpret_cast<float4*>(out + (size_t)q * C_DIM + lane * 4) = acc;
}

// ---------------------------------------------------------------------------
extern "C" void kernel_launch(void* const* d_in, const int* in_sizes, int n_in,
                              void* d_out, int out_size, void* d_ws, size_t ws_size,
                              hipStream_t stream) {
    const float* query = (const float*)d_in[0];
    // d_in[1] = key (unused by reference)
    const float* value = (const float*)d_in[2];
    const float* rp    = (const float*)d_in[3];
    // d_in[4] = spatial_shapes (constant [[128,256],[128,256]], hardcoded)
    const float* Woff  = (const float*)d_in[5];
    const float* boff  = (const float*)d_in[6];
    const float* Wattn = (const float*)d_in[7];
    const float* battn = (const float*)d_in[8];
    float* out = (float*)d_out;

    char* ws = (char*)d_ws;
    float4* samples = (float4*)(ws + WS_SAMPLES_OFF);  // [Q,8] float4 = 5.12 MB
    float*  Wt      = (float*) (ws + WS_WT_OFF);       // [24][256]
    float*  bias    = (float*) (ws + WS_BIAS_OFF);     // [24]

    setup_w_kernel<<<1, 256, 0, stream>>>(Woff, boff, Wattn, battn, Wt, bias);
    proj_gemm_kernel<<<625, 256, 0, stream>>>(query, rp, Wt, bias, samples);
    const int blocks = (Q_DIM * 64 + 255) / 256;   // one wave per query
    deform_sample_kernel<<<blocks, 256, 0, stream>>>(value, samples, out);
}

// Round 9
// 275.565 us; speedup vs baseline: 1.0760x; 1.0760x over previous
//
#include <hip/hip_runtime.h>

// Deformable attention, single head, Lv=2, P=4.
// K0 setup (Wt transpose+bias), K1 proj v4 (scalar-W GEMM, K-split waves),
// K2 sample (proven gather) split into TWO half dispatches for rocprof
// visibility of whichever kernel is slowest.

#define C_DIM 256
#define Q_DIM 40000
#define H_IMG 128
#define W_IMG 256
#define NV    (H_IMG * W_IMG)

#define WS_SAMPLES_OFF 0
#define WS_WT_OFF      5120000
#define WS_BIAS_OFF    5144576

// ---------------------------------------------------------------------------
// Kernel 0: W transpose + bias concat (1 block, trivial).
// Wt[j][c]: row j = output column j, contiguous in K (c).
// ---------------------------------------------------------------------------
__global__ __launch_bounds__(256) void setup_w_kernel(
    const float* __restrict__ Woff,  const float* __restrict__ boff,
    const float* __restrict__ Wattn, const float* __restrict__ battn,
    float* __restrict__ Wt, float* __restrict__ bias)
{
    const int tid = threadIdx.x;
    for (int i = tid; i < 4096; i += 256) {          // W_off [256,16] -> rows 0..15
        int c = i >> 4, j = i & 15;
        Wt[j * 256 + c] = Woff[i];
    }
    for (int i = tid; i < 2048; i += 256) {          // W_attn [256,8] -> rows 16..23
        int c = i >> 3, j = i & 7;
        Wt[(16 + j) * 256 + c] = Wattn[i];
    }
    if (tid < 16)      bias[tid] = boff[tid];
    else if (tid < 24) bias[tid] = battn[tid - 16];
}

// ---------------------------------------------------------------------------
// Kernel 1 (v4): proj GEMM, 625 blocks x 256 thr; tile = 64 queries.
// Thread t owns query r = t&63, computes ALL 24 outputs; wave w = t>>6
// covers k in {p*128 + w*32 .. +32} for phase p = 0,1 (disjoint K cover).
// W addresses use readfirstlane(w) -> provably wave-uniform -> s_load.
// ---------------------------------------------------------------------------
__global__ __launch_bounds__(256) void proj_gemm4_kernel(
    const float* __restrict__ query,
    const float* __restrict__ rp,
    const float* __restrict__ Wt,      // [24][256] in ws
    const float* __restrict__ bias,    // [24] in ws
    float4* __restrict__ samples)      // [Q][8] in ws
{
    __shared__ float Qt[128 * 65];       // phase k-chunk transposed: Qt[kk][r]
    __shared__ float red[3 * 64 * 25];   // partial dump from waves 1..3

    const int tid = threadIdx.x;
    const int r   = tid & 63;                          // query within tile
    const int wv  = tid >> 6;
    const int wu  = __builtin_amdgcn_readfirstlane(wv); // scalar wave id
    const int q0  = blockIdx.x * 64;                    // 625 * 64 = 40000

    float acc[24];
#pragma unroll
    for (int j = 0; j < 24; ++j) acc[j] = 0.f;

#pragma unroll
    for (int p = 0; p < 2; ++p) {
        // ---- stage k-half transposed: thread t loads row t>>2, 32 floats ----
        {
            const int row = tid >> 2;
            const int k0  = (tid & 3) * 32;
            const float* src = query + (size_t)(q0 + row) * C_DIM + p * 128 + k0;
#pragma unroll
            for (int iq = 0; iq < 8; ++iq) {
                float4 v = *reinterpret_cast<const float4*>(src + iq * 4);
                Qt[(k0 + iq * 4 + 0) * 65 + row] = v.x;
                Qt[(k0 + iq * 4 + 1) * 65 + row] = v.y;
                Qt[(k0 + iq * 4 + 2) * 65 + row] = v.z;
                Qt[(k0 + iq * 4 + 3) * 65 + row] = v.w;
            }
        }
        __syncthreads();

        // ---- wave w consumes k in [p*128 + wu*32, +32) ----
        const int kk0 = wu * 32;                 // index within staged half
        const int kg0 = p * 128 + wu * 32;       // global k for W
#pragma unroll
        for (int i = 0; i < 32; ++i) {
            const float qv = Qt[(kk0 + i) * 65 + r];   // conflict-free b32
#pragma unroll
            for (int j = 0; j < 24; ++j) {
                acc[j] = fmaf(Wt[j * 256 + kg0 + i], qv, acc[j]);  // s_load operand
            }
        }
        __syncthreads();
    }

    // ---- cross-wave reduce: waves 1..3 dump, wave 0 finishes ----
    if (wv > 0) {
        float* dst = red + ((wv - 1) * 64 + r) * 25;
#pragma unroll
        for (int j = 0; j < 24; ++j) dst[j] = acc[j];
    }
    __syncthreads();

    if (tid < 64) {
        const int q = q0 + r;
        float s[24];
#pragma unroll
        for (int j = 0; j < 24; ++j) {
            s[j] = acc[j] + bias[j]
                 + red[(0 * 64 + r) * 25 + j]
                 + red[(1 * 64 + r) * 25 + j]
                 + red[(2 * 64 + r) * 25 + j];
        }

        float4 rp4 = *reinterpret_cast<const float4*>(rp + (size_t)q * 4); // l0x,l0y,l1x,l1y

        float mx = s[16];
#pragma unroll
        for (int k = 1; k < 8; ++k) mx = fmaxf(mx, s[16 + k]);
        float e[8], den = 0.f;
#pragma unroll
        for (int k = 0; k < 8; ++k) { e[k] = __expf(s[16 + k] - mx); den += e[k]; }
        const float rd = 1.0f / den;

#pragma unroll
        for (int smp = 0; smp < 8; ++smp) {
            const float refx = (smp >= 4) ? rp4.z : rp4.x;
            const float refy = (smp >= 4) ? rp4.w : rp4.y;
            const float ix = refx * (float)W_IMG + s[2 * smp]     - 0.5f;
            const float iy = refy * (float)H_IMG + s[2 * smp + 1] - 0.5f;
            samples[(size_t)q * 8 + smp] = make_float4(ix, iy, e[smp] * rd, 0.f);
        }
    }
}

// ---------------------------------------------------------------------------
// Kernel 2: bilinear gather + weighted accumulate (proven; now takes q_base
// and is launched twice over half the queries each, for rocprof visibility).
// ---------------------------------------------------------------------------
__global__ __launch_bounds__(256) void deform_sample_kernel(
    const float* __restrict__ value,    // [2, NV, 256]
    const float4* __restrict__ samples, // [Q, 8]
    float* __restrict__ out,            // [Q, 256]
    int q_base, int q_count)
{
    const int lane = threadIdx.x & 63;
    const int qi = (blockIdx.x * blockDim.x + threadIdx.x) >> 6;
    if (qi >= q_count) return;
    const int q = q_base + qi;

    float4 acc = make_float4(0.f, 0.f, 0.f, 0.f);

#pragma unroll
    for (int smp = 0; smp < 8; ++smp) {
        float4 rec = samples[(size_t)q * 8 + smp];  // broadcast load
        const float* base = value + (size_t)(smp >> 2) * ((size_t)NV * C_DIM);

        float ix = rec.x, iy = rec.y, aw = rec.z;
        float x0f = floorf(ix), y0f = floorf(iy);
        float fx = ix - x0f, fy = iy - y0f;
        int x0 = (int)x0f, y0 = (int)y0f;
        int x1 = x0 + 1,   y1 = y0 + 1;

        bool vx0 = (unsigned)x0 < W_IMG;
        bool vx1 = (unsigned)x1 < W_IMG;
        bool vy0 = (unsigned)y0 < H_IMG;
        bool vy1 = (unsigned)y1 < H_IMG;

        int xc0 = min(max(x0, 0), W_IMG - 1);
        int xc1 = min(max(x1, 0), W_IMG - 1);
        int yc0 = min(max(y0, 0), H_IMG - 1);
        int yc1 = min(max(y1, 0), H_IMG - 1);

        float wx0 = 1.f - fx, wx1 = fx;
        float wy0 = 1.f - fy, wy1 = fy;
        float w00 = (vx0 && vy0) ? wx0 * wy0 * aw : 0.f;
        float w01 = (vx1 && vy0) ? wx1 * wy0 * aw : 0.f;
        float w10 = (vx0 && vy1) ? wx0 * wy1 * aw : 0.f;
        float w11 = (vx1 && vy1) ? wx1 * wy1 * aw : 0.f;

        const int ch = lane * 4;
        float4 v00 = *reinterpret_cast<const float4*>(base + (size_t)(yc0 * W_IMG + xc0) * C_DIM + ch);
        float4 v01 = *reinterpret_cast<const float4*>(base + (size_t)(yc0 * W_IMG + xc1) * C_DIM + ch);
        float4 v10 = *reinterpret_cast<const float4*>(base + (size_t)(yc1 * W_IMG + xc0) * C_DIM + ch);
        float4 v11 = *reinterpret_cast<const float4*>(base + (size_t)(yc1 * W_IMG + xc1) * C_DIM + ch);

        acc.x += w00 * v00.x + w01 * v01.x + w10 * v10.x + w11 * v11.x;
        acc.y += w00 * v00.y + w01 * v01.y + w10 * v10.y + w11 * v11.y;
        acc.z += w00 * v00.z + w01 * v01.z + w10 * v10.z + w11 * v11.z;
        acc.w += w00 * v00.w + w01 * v01.w + w10 * v10.w + w11 * v11.w;
    }

    *reinterpret_cast<float4*>(out + (size_t)q * C_DIM + lane * 4) = acc;
}

// ---------------------------------------------------------------------------
extern "C" void kernel_launch(void* const* d_in, const int* in_sizes, int n_in,
                              void* d_out, int out_size, void* d_ws, size_t ws_size,
                              hipStream_t stream) {
    const float* query = (const float*)d_in[0];
    // d_in[1] = key (unused by reference)
    const float* value = (const float*)d_in[2];
    const float* rp    = (const float*)d_in[3];
    // d_in[4] = spatial_shapes (constant [[128,256],[128,256]], hardcoded)
    const float* Woff  = (const float*)d_in[5];
    const float* boff  = (const float*)d_in[6];
    const float* Wattn = (const float*)d_in[7];
    const float* battn = (const float*)d_in[8];
    float* out = (float*)d_out;

    char* ws = (char*)d_ws;
    float4* samples = (float4*)(ws + WS_SAMPLES_OFF);  // [Q,8] float4 = 5.12 MB
    float*  Wt      = (float*) (ws + WS_WT_OFF);       // [24][256]
    float*  bias    = (float*) (ws + WS_BIAS_OFF);     // [24]

    setup_w_kernel<<<1, 256, 0, stream>>>(Woff, boff, Wattn, battn, Wt, bias);
    proj_gemm4_kernel<<<625, 256, 0, stream>>>(query, rp, Wt, bias, samples);

    const int qh = Q_DIM / 2;                          // 20000
    const int blocks_h = (qh * 64 + 255) / 256;        // 5000
    deform_sample_kernel<<<blocks_h, 256, 0, stream>>>(value, samples, out, 0,  qh);
    deform_sample_kernel<<<blocks_h, 256, 0, stream>>>(value, samples, out, qh, qh);
}